// Round 2
// baseline (886.063 us; speedup 1.0000x reference)
//
#include <hip/hip_runtime.h>

// WindowedAttention on MI355X (gfx950).
// B=8, H=W=64, C=1024, WS=14 -> H_=W_=70, 5x5 windows/image, Bw=200, N_=196.
// heads=16, D=64, scale=0.125.
// Pipeline: winpad -> Wt transposes -> QKV GEMM (bf16 MFMA, scatter to Q/K/V
//           per-(window,head) [196][64]) -> LN(q,k) in-place ->
//           per-(window,head) MFMA attention -> proj GEMM -> d_out (f32).
// Scratch budget: peak 329,515,008 bytes (AO aliases Aw).

using u16 = unsigned short;
typedef u16   u16x4  __attribute__((ext_vector_type(4)));
typedef u16   u16x8  __attribute__((ext_vector_type(8)));
typedef __bf16 bf16x8 __attribute__((ext_vector_type(8)));
typedef float f32x4  __attribute__((ext_vector_type(4)));

__device__ __forceinline__ u16 f2bf(float f){
  union { float f; unsigned u; } v; v.f = f;
  return (u16)((v.u + 0x7fffu + ((v.u >> 16) & 1u)) >> 16);   // RNE
}
__device__ __forceinline__ float bf2f(u16 h){
  union { unsigned u; float f; } v; v.u = ((unsigned)h) << 16;
  return v.f;
}

// ---------------------------------------------------------------------------
// K0: window partition + zero pad + f32->bf16.  x(8,4096,1024) -> Aw(39200,1024)
// row = win*196 + t ; win = b*25 + wr*5 + wc ; t = th*14 + tw
__global__ __launch_bounds__(256) void winpad_kernel(const float* __restrict__ x,
                                                     u16* __restrict__ Aw){
  const int row = blockIdx.x;                 // 0..39199
  const int win = row / 196, t = row % 196;
  const int b = win / 25, wrc = win % 25;
  const int wr = wrc / 5, wc = wrc % 5;
  const int th = t / 14, tw = t % 14;
  const int gh = wr*14 + th, gw = wc*14 + tw;
  u16* dst = Aw + (long)row * 1024;
  const int c = threadIdx.x * 4;
  u16x4 o;
  if (gh < 64 && gw < 64){
    const float4 v = *(const float4*)(x + ((long)b*4096 + gh*64 + gw)*1024 + c);
    o[0] = f2bf(v.x); o[1] = f2bf(v.y); o[2] = f2bf(v.z); o[3] = f2bf(v.w);
  } else {
    o[0] = 0; o[1] = 0; o[2] = 0; o[3] = 0;
  }
  *(u16x4*)(dst + c) = o;
}

// ---------------------------------------------------------------------------
// K0b: transpose + convert: in (R,C) f32 -> out (C,R) bf16   (B^T for MFMA)
__global__ __launch_bounds__(256) void transpose_kernel(const float* __restrict__ in,
                                                        u16* __restrict__ out,
                                                        int R, int C){
  __shared__ float tile[32][33];
  const int tx = threadIdx.x & 31, ty = threadIdx.x >> 5;
  const int c0 = blockIdx.x * 32, r0 = blockIdx.y * 32;
  #pragma unroll
  for (int j = 0; j < 4; ++j)
    tile[ty + j*8][tx] = in[(long)(r0 + ty + j*8)*C + c0 + tx];
  __syncthreads();
  #pragma unroll
  for (int j = 0; j < 4; ++j){
    int oc = ty + j*8;
    out[(long)(c0 + oc)*R + r0 + tx] = f2bf(tile[tx][oc]);
  }
}

// ---------------------------------------------------------------------------
// GEMM: C[m][n] = sum_k A[m][k]*Bt[n][k] + bias[n]
// 128x128 tile, BK=64, 4 waves (2x2), each wave 64x64 = 4x4 16x16x32 frags.
// LDS 16B-chunk XOR swizzle (chunk ^= row&7) -> conflict-free ds_read_b128.
// MODE 0: f32 row-major out (C0). MODE 1: scatter bf16 into q/k/v buffers
//         (C0,C1,C2) laid out [win*16+head][196][64].
template<int MODE>
__global__ __launch_bounds__(256, 2)
void gemm_bt_kernel(const u16* __restrict__ A, const u16* __restrict__ Bt,
                    const float* __restrict__ bias, void* __restrict__ C0,
                    void* __restrict__ C1, void* __restrict__ C2,
                    int M, int N, int K, int NT){
  __shared__ __align__(16) u16 As[128*64];
  __shared__ __align__(16) u16 Bs[128*64];
  const int tid = threadIdx.x;
  const int l = tid & 63;
  const int w = tid >> 6;
  const int wm = w >> 1, wn = w & 1;
  const int bid = blockIdx.x;
  const int tm = bid / NT, tn = bid % NT;

  f32x4 acc[4][4];
  #pragma unroll
  for (int i = 0; i < 4; ++i)
    #pragma unroll
    for (int j = 0; j < 4; ++j) acc[i][j] = (f32x4){0.f,0.f,0.f,0.f};

  const int srow = tid >> 3;   // 0..31
  const int skc  = tid & 7;    // 0..7
  const u16* aptr[4]; const u16* bptr[4]; int wofs[4];
  #pragma unroll
  for (int it = 0; it < 4; ++it){
    const int m = it*32 + srow;
    long ra = (long)tm*128 + m; if (ra > (long)M - 1) ra = M - 1;   // clamp edge tile
    aptr[it] = A  + ra*K + skc*8;
    bptr[it] = Bt + ((long)tn*128 + m)*K + skc*8;
    wofs[it] = m*64 + ((skc ^ (m & 7)) * 8);
  }
  u16x8 rA[4], rB[4];
  #pragma unroll
  for (int it = 0; it < 4; ++it){
    rA[it] = *(const u16x8*)aptr[it];
    rB[it] = *(const u16x8*)bptr[it];
  }

  const int nk = K >> 6;
  for (int kk = 0; kk < nk; ++kk){
    __syncthreads();
    #pragma unroll
    for (int it = 0; it < 4; ++it){
      *(u16x8*)&As[wofs[it]] = rA[it];
      *(u16x8*)&Bs[wofs[it]] = rB[it];
    }
    __syncthreads();
    if (kk + 1 < nk){
      #pragma unroll
      for (int it = 0; it < 4; ++it){                 // prefetch next K-slice
        rA[it] = *(const u16x8*)(aptr[it] + (kk+1)*64);
        rB[it] = *(const u16x8*)(bptr[it] + (kk+1)*64);
      }
    }
    #pragma unroll
    for (int ks = 0; ks < 2; ++ks){
      bf16x8 af[4], bfr[4];
      const int kc = ks*4 + (l >> 4);
      #pragma unroll
      for (int mi = 0; mi < 4; ++mi){
        const int m = wm*64 + mi*16 + (l & 15);
        af[mi] = *(const bf16x8*)&As[m*64 + ((kc ^ (m & 7)) * 8)];
      }
      #pragma unroll
      for (int ni = 0; ni < 4; ++ni){
        const int n = wn*64 + ni*16 + (l & 15);
        bfr[ni] = *(const bf16x8*)&Bs[n*64 + ((kc ^ (n & 7)) * 8)];
      }
      #pragma unroll
      for (int mi = 0; mi < 4; ++mi)
        #pragma unroll
        for (int ni = 0; ni < 4; ++ni)
          acc[mi][ni] = __builtin_amdgcn_mfma_f32_16x16x32_bf16(af[mi], bfr[ni], acc[mi][ni], 0, 0, 0);
    }
  }

  // epilogue: C/D layout col = l&15, row = (l>>4)*4 + r  [m89/m91]
  const int row0 = tm*128 + wm*64 + (l >> 4)*4;
  const int col0 = tn*128 + wn*64 + (l & 15);
  if (MODE == 0){
    float* out = (float*)C0;
    #pragma unroll
    for (int ni = 0; ni < 4; ++ni){
      const int c = col0 + ni*16;
      const float bv = bias[c];
      #pragma unroll
      for (int mi = 0; mi < 4; ++mi){
        #pragma unroll
        for (int r = 0; r < 4; ++r){
          const int rg = row0 + mi*16 + r;
          if (rg < M) out[(long)rg*N + c] = acc[mi][ni][r] + bv;
        }
      }
    }
  } else {
    // part and head are wave-uniform: col tile 128 never crosses a 1024-part,
    // and ni*16+(l&15) stays inside one 64-col head block.
    const int part = tn >> 3;                    // 0=q 1=k 2=v
    const int head = (tn*2 + wn) & 15;
    u16* dp = (u16*)(part == 0 ? C0 : (part == 1 ? C1 : C2));
    #pragma unroll
    for (int ni = 0; ni < 4; ++ni){
      const int c = col0 + ni*16;
      const float bv = bias[c];
      const int d = ni*16 + (l & 15);
      #pragma unroll
      for (int mi = 0; mi < 4; ++mi){
        #pragma unroll
        for (int r = 0; r < 4; ++r){
          const int rg = row0 + mi*16 + r;
          if (rg < M){
            const int win = rg / 196, t = rg - win*196;
            dp[((long)(win*16 + head)*196 + t)*64 + d] = f2bf(acc[mi][ni][r] + bv);
          }
        }
      }
    }
  }
}

// ---------------------------------------------------------------------------
// K2: LayerNorm over full C=1024 for q and k, in-place on the per-head layout.
// One wave per token: lane l covers head=l>>2, d-range (l&3)*16..+15.
__global__ __launch_bounds__(256) void ln_qk_kernel(u16* __restrict__ qb,
    u16* __restrict__ kb,
    const float* __restrict__ qn_w, const float* __restrict__ qn_b,
    const float* __restrict__ kn_w, const float* __restrict__ kn_b){
  const int l = threadIdx.x & 63, w = threadIdx.x >> 6;
  const int token = blockIdx.x*4 + w;                 // < 39200
  const int win = token / 196, t = token - win*196;
  const int head = l >> 2, dq = (l & 3) * 16;
  const long ofs = ((long)(win*16 + head)*196 + t)*64 + dq;
  const int cb = head*64 + dq;
  #pragma unroll
  for (int part = 0; part < 2; ++part){
    u16* src = (part ? kb : qb) + ofs;
    float v[16];
    u16x8 a  = *(const u16x8*)(src);
    u16x8 b2 = *(const u16x8*)(src + 8);
    #pragma unroll
    for (int j = 0; j < 8; ++j){ v[j] = bf2f(a[j]); v[8+j] = bf2f(b2[j]); }
    float s = 0.f, s2 = 0.f;
    #pragma unroll
    for (int j = 0; j < 16; ++j){ s += v[j]; s2 += v[j]*v[j]; }
    #pragma unroll
    for (int m = 1; m < 64; m <<= 1){
      s  += __shfl_xor(s,  m, 64);
      s2 += __shfl_xor(s2, m, 64);
    }
    const float mean = s * (1.f/1024.f);
    const float var  = s2 * (1.f/1024.f) - mean*mean;
    const float rs   = rsqrtf(var + 1e-5f);
    const float* gw = part ? kn_w : qn_w;
    const float* gb = part ? kn_b : qn_b;
    u16x8 o0, o1;
    #pragma unroll
    for (int j = 0; j < 8; ++j){
      o0[j] = f2bf((v[j]   - mean)*rs*gw[cb+j]   + gb[cb+j]);
      o1[j] = f2bf((v[8+j] - mean)*rs*gw[cb+8+j] + gb[cb+8+j]);
    }
    *(u16x8*)src       = o0;
    *(u16x8*)(src + 8) = o1;
  }
}

// ---------------------------------------------------------------------------
// K3: attention per (window, head). 4 waves cooperate per 16-row Q tile.
// Ks: [208][64] swizzled (keys 196..207 zero, masked to -inf in S).
// Vs: V^T [64][224] swizzled (keys 196..223 zero). Ps: P [16][224] bf16.
__device__ __forceinline__ int vslot(int kc, int x){
  return kc ^ (kc < 24 ? (x & 7) : (x & 3));   // keep XOR bijective within 0..27
}

__global__ __launch_bounds__(256, 2)
void attn_kernel(const u16* __restrict__ qb_all, const u16* __restrict__ kb_all,
                 const u16* __restrict__ vb_all, u16* __restrict__ attn_out){
  __shared__ __align__(16) u16 Ks[208*64];
  __shared__ __align__(16) u16 Vs[64*224];
  __shared__ __align__(16) u16 Ps[16*224];
  __shared__ float redmax[4][16];
  __shared__ float redsum[4][16];
  const int tid = threadIdx.x, l = tid & 63, w = tid >> 6;
  const int wh = blockIdx.x;
  const int win = wh >> 4, head = wh & 15;

  { // stage K (LN'd), zero-pad rows 196..207
    const u16* kb = kb_all + (long)wh * 196 * 64;
    for (int i = tid; i < 208*8; i += 256){
      const int n = i >> 3, kc = i & 7;
      u16x8 val = (u16x8){0,0,0,0,0,0,0,0};
      if (n < 196) val = *(const u16x8*)(kb + n*64 + kc*8);
      *(u16x8*)&Ks[n*64 + ((kc ^ (n & 7))*8)] = val;
    }
  }
  { // stage V^T, transposed + swizzled
    const u16* vb = vb_all + (long)wh * 196 * 64;
    for (int i = tid; i < 196*8; i += 256){
      const int t = i >> 3, kc = i & 7;
      u16x8 val = *(const u16x8*)(vb + t*64 + kc*8);
      #pragma unroll
      for (int j = 0; j < 8; ++j){
        const int dd = kc*8 + j;
        Vs[dd*224 + vslot(t >> 3, (dd & 7) ^ ((dd >> 3) & 7))*8 + (t & 7)] = val[j];
      }
    }
    for (int i = tid; i < 64*28; i += 256){            // zero keys 196..223
      const int dd = i / 28, k = 196 + (i % 28);
      Vs[dd*224 + vslot(k >> 3, (dd & 7) ^ ((dd >> 3) & 7))*8 + (k & 7)] = 0;
    }
    for (int i = tid; i < 16*16; i += 256){            // zero P cols 208..223
      const int q = i >> 4, k = 208 + (i & 15);
      Ps[q*224 + vslot(k >> 3, q & 7)*8 + (k & 7)] = 0;
    }
  }
  __syncthreads();

  const u16* qb = qb_all + (long)wh * 196 * 64;
  const int b_img = win / 25, wrc = win % 25;
  const int wr = wrc / 5, wc = wrc % 5;

  for (int mt = 0; mt < 13; ++mt){
    // Q A-frags straight from global (L2-resident)
    bf16x8 aq[2];
    {
      int qr = mt*16 + (l & 15); if (qr > 195) qr = 195;
      const u16* qp = qb + qr*64 + (l >> 4)*8;
      aq[0] = *(const bf16x8*)qp;
      aq[1] = *(const bf16x8*)(qp + 32);
    }
    // S tiles: wave w owns key-tiles nt = w, w+4, w+8 (+12 for w==0)
    f32x4 s[4];
    #pragma unroll
    for (int c = 0; c < 4; ++c){
      const int nt = w + c*4;
      if (nt <= 12){
        f32x4 a2 = (f32x4){0.f,0.f,0.f,0.f};
        #pragma unroll
        for (int ks = 0; ks < 2; ++ks){
          const int n = nt*16 + (l & 15);
          const int kc = ks*4 + (l >> 4);
          bf16x8 bk = *(const bf16x8*)&Ks[n*64 + ((kc ^ (n & 7))*8)];
          a2 = __builtin_amdgcn_mfma_f32_16x16x32_bf16(aq[ks], bk, a2, 0, 0, 0);
        }
        s[c] = a2;
      }
    }
    // scale + mask fake keys (cols 196..207 live in tile 12)
    float mx[4];
    #pragma unroll
    for (int r = 0; r < 4; ++r) mx[r] = -3.0e38f;
    #pragma unroll
    for (int c = 0; c < 4; ++c){
      const int nt = w + c*4;
      if (nt <= 12){
        #pragma unroll
        for (int r = 0; r < 4; ++r){
          float sv = s[c][r] * 0.125f;
          if (nt == 12 && (l & 15) >= 4) sv = -3.0e38f;
          s[c][r] = sv;
          mx[r] = fmaxf(mx[r], sv);
        }
      }
    }
    #pragma unroll
    for (int m = 1; m < 16; m <<= 1)
      #pragma unroll
      for (int r = 0; r < 4; ++r)
        mx[r] = fmaxf(mx[r], __shfl_xor(mx[r], m, 64));
    if ((l & 15) == 0){
      #pragma unroll
      for (int r = 0; r < 4; ++r) redmax[w][(l >> 4)*4 + r] = mx[r];
    }
    __syncthreads();
    float Mr[4], sm[4];
    #pragma unroll
    for (int r = 0; r < 4; ++r){
      const int row = (l >> 4)*4 + r;
      Mr[r] = fmaxf(fmaxf(redmax[0][row], redmax[1][row]),
                    fmaxf(redmax[2][row], redmax[3][row]));
      sm[r] = 0.f;
    }
    #pragma unroll
    for (int c = 0; c < 4; ++c){
      const int nt = w + c*4;
      if (nt <= 12){
        const int k = nt*16 + (l & 15);
        #pragma unroll
        for (int r = 0; r < 4; ++r){
          const float p = __expf(s[c][r] - Mr[r]);
          sm[r] += p;
          const int q = (l >> 4)*4 + r;
          Ps[q*224 + vslot(k >> 3, q & 7)*8 + (k & 7)] = f2bf(p);
        }
      }
    }
    #pragma unroll
    for (int m = 1; m < 16; m <<= 1)
      #pragma unroll
      for (int r = 0; r < 4; ++r)
        sm[r] += __shfl_xor(sm[r], m, 64);
    if ((l & 15) == 0){
      #pragma unroll
      for (int r = 0; r < 4; ++r) redsum[w][(l >> 4)*4 + r] = sm[r];
    }
    __syncthreads();
    // PV: wave w owns d-tile w (cols w*16..w*16+15)
    f32x4 o = (f32x4){0.f,0.f,0.f,0.f};
    #pragma unroll
    for (int ks = 0; ks < 7; ++ks){
      const int kc = ks*4 + (l >> 4);
      const int q = l & 15;
      bf16x8 pa = *(const bf16x8*)&Ps[q*224 + vslot(kc, q & 7)*8];
      const int dd = w*16 + (l & 15);
      bf16x8 vv = *(const bf16x8*)&Vs[dd*224 + vslot(kc, (dd & 7) ^ ((dd >> 3) & 7))*8];
      o = __builtin_amdgcn_mfma_f32_16x16x32_bf16(pa, vv, o, 0, 0, 0);
    }
    // store (un-windowed, crop pads), deferred 1/sum
    #pragma unroll
    for (int r = 0; r < 4; ++r){
      const int q = mt*16 + (l >> 4)*4 + r;
      if (q < 196){
        const int row = (l >> 4)*4 + r;
        const float denom = redsum[0][row] + redsum[1][row] + redsum[2][row] + redsum[3][row];
        const float val = o[r] / denom;
        const int th = q / 14, tw2 = q % 14;
        const int gh = wr*14 + th, gw = wc*14 + tw2;
        if (gh < 64 && gw < 64){
          const long orow = (long)b_img*4096 + gh*64 + gw;
          attn_out[orow*1024 + head*64 + w*16 + (l & 15)] = f2bf(val);
        }
      }
    }
    __syncthreads();
  }
}

// ---------------------------------------------------------------------------
extern "C" void kernel_launch(void* const* d_in, const int* in_sizes, int n_in,
                              void* d_out, int out_size, void* d_ws, size_t ws_size,
                              hipStream_t stream){
  (void)in_sizes; (void)n_in; (void)out_size; (void)ws_size;
  const float* x      = (const float*)d_in[0];
  const float* qkv_w  = (const float*)d_in[1];
  const float* qkv_b  = (const float*)d_in[2];
  const float* proj_w = (const float*)d_in[3];
  const float* proj_b = (const float*)d_in[4];
  const float* qn_w   = (const float*)d_in[5];
  const float* qn_b   = (const float*)d_in[6];
  const float* kn_w   = (const float*)d_in[7];
  const float* kn_b   = (const float*)d_in[8];
  float* out = (float*)d_out;
  char* ws = (char*)d_ws;

  u16* Aw = (u16*)(ws);                  // 39200*1024*2 = 80,281,600 B
  u16* Wq = (u16*)(ws +  80281600);      //  3072*1024*2 =  6,291,456 B
  u16* Wp = (u16*)(ws +  86573056);      //  1024*1024*2 =  2,097,152 B
  u16* Qb = (u16*)(ws +  88670208);      //  3200*196*64*2 = 80,281,600 B
  u16* Kb = (u16*)(ws + 168951808);      //  3200*196*64*2 = 80,281,600 B
  u16* Vb = (u16*)(ws + 249233408);      //  3200*196*64*2 = 80,281,600 B
  u16* AO = Aw;                          // alias: Aw dead after QKV GEMM; 67,108,864 B
  // peak scratch use: 329,515,008 bytes

  winpad_kernel<<<39200, 256, 0, stream>>>(x, Aw);
  transpose_kernel<<<dim3(96, 32), 256, 0, stream>>>(qkv_w, Wq, 1024, 3072);
  transpose_kernel<<<dim3(32, 32), 256, 0, stream>>>(proj_w, Wp, 1024, 1024);
  gemm_bt_kernel<1><<<307*24, 256, 0, stream>>>(Aw, Wq, qkv_b, Qb, Kb, Vb, 39200, 3072, 1024, 24);
  ln_qk_kernel<<<9800, 256, 0, stream>>>(Qb, Kb, qn_w, qn_b, kn_w, kn_b);
  attn_kernel<<<3200, 256, 0, stream>>>(Qb, Kb, Vb, AO);
  gemm_bt_kernel<0><<<256*8, 256, 0, stream>>>(AO, Wp, proj_b, out, nullptr, nullptr, 32768, 1024, 1024, 8);
}